// Round 1
// baseline (247.509 us; speedup 1.0000x reference)
//
#include <hip/hip_runtime.h>
#include <math.h>

#define NB 16
#define NL 1024
#define NH 8
#define NE 64
#define NWIN 1024
#define NG 64

__device__ inline float wave_sum(float v) {
    #pragma unroll
    for (int off = 32; off > 0; off >>= 1)
        v += __shfl_xor(v, off, 64);
    return v;
}
__device__ inline float wave_max(float v) {
    #pragma unroll
    for (int off = 32; off > 0; off >>= 1)
        v = fmaxf(v, __shfl_xor(v, off, 64));
    return v;
}

// Kernel A: t[b,h,l] = tanh(x_row[r] . mlp_w[c] + mlp_b[c])
// with r = b*1024 + h*128 + l/8, c = l%8  (raw-reshape index mixing)
// One wave per row r; mlp_w (8x1024 = 32KB) staged in LDS.
__global__ __launch_bounds__(256) void k_tanh_mlp(
    const float* __restrict__ x, const float* __restrict__ mlp_w,
    const float* __restrict__ mlp_b, float* __restrict__ t_out)
{
    __shared__ float w_lds[8][NWIN];
    int tid = threadIdx.x;
    const float4* w4 = (const float4*)mlp_w;
    float4* wl4 = (float4*)&w_lds[0][0];
    #pragma unroll
    for (int i = 0; i < 8; ++i)
        wl4[tid + 256 * i] = w4[tid + 256 * i];
    __syncthreads();

    int wave = tid >> 6, lane = tid & 63;
    int r = blockIdx.x * 4 + wave;                  // [0, 16384)
    const float4* xr = (const float4*)(x + (size_t)r * NWIN);
    float acc[8] = {0.f,0.f,0.f,0.f,0.f,0.f,0.f,0.f};
    #pragma unroll
    for (int it = 0; it < 4; ++it) {
        float4 xv = xr[it * 64 + lane];
        int idx = (it * 64 + lane) * 4;
        #pragma unroll
        for (int c = 0; c < 8; ++c) {
            acc[c] += xv.x * w_lds[c][idx]     + xv.y * w_lds[c][idx + 1]
                    + xv.z * w_lds[c][idx + 2] + xv.w * w_lds[c][idx + 3];
        }
    }
    #pragma unroll
    for (int c = 0; c < 8; ++c) acc[c] = wave_sum(acc[c]);
    if (lane == 0) {
        int b = r >> 10, rr = r & 1023;
        int h = rr >> 7, l8 = rr & 127;
        float* dst = t_out + ((b * NH + h) * NL) + l8 * 8;
        #pragma unroll
        for (int c = 0; c < 8; ++c)
            dst[c] = tanhf(acc[c] + mlp_b[c]);
    }
}

// Kernel B: qp[b,h,e] = sum_l max(t,0)*q[b,l,h,e]; qn with min(t,0).
// grid = B*H*4 (4 l-chunks), block 256 (4 waves, lane = e). atomicAdd into
// zeroed qp/qn.
__global__ __launch_bounds__(256) void k_qpn(
    const float* __restrict__ q, const float* __restrict__ t,
    float* __restrict__ qp, float* __restrict__ qn)
{
    int blk = blockIdx.x;
    int lc = blk & 3;
    int bh = blk >> 2;                // b*8+h
    int b = bh >> 3, h = bh & 7;
    int wave = threadIdx.x >> 6, lane = threadIdx.x & 63;
    const float* tb = t + bh * NL;
    float accp = 0.f, accn = 0.f;
    for (int i = 0; i < 64; ++i) {
        int l = lc * 256 + i * 4 + wave;
        float tv = tb[l];
        float qv = q[(((size_t)(b * NL + l)) * NH + h) * NE + lane];
        accp += fmaxf(tv, 0.f) * qv;
        accn += fminf(tv, 0.f) * qv;
    }
    __shared__ float red[2][4][64];
    red[0][wave][lane] = accp;
    red[1][wave][lane] = accn;
    __syncthreads();
    if (wave == 0) {
        float sp = red[0][0][lane] + red[0][1][lane] + red[0][2][lane] + red[0][3][lane];
        atomicAdd(&qp[bh * NE + lane], sp);
    } else if (wave == 1) {
        float sn = red[1][0][lane] + red[1][1][lane] + red[1][2][lane] + red[1][3][lane];
        atomicAdd(&qn[bh * NE + lane], sn);
    }
}

// Kernel D: per (b,h,chunk of 128 s):
//   phase A: Ap/An via wave dot of k row with qp/qn (held in lane regs)
//   phase B: per-s softmax over g (lane = g) + outer-product V accumulation
//   (thread owns g = tid&63 and 16 e's), atomicAdd into zeroed out.
__global__ __launch_bounds__(256) void k_attn_out(
    const float* __restrict__ keys, const float* __restrict__ values,
    const float* __restrict__ sel_W,
    const float* __restrict__ qp, const float* __restrict__ qn,
    float* __restrict__ out)
{
    const int NC = 8, SC = 128;
    int blk = blockIdx.x;
    int chunk = blk & (NC - 1);
    int bh = blk >> 3;
    int b = bh >> 3, h = bh & 7;
    int wave = threadIdx.x >> 6, lane = threadIdx.x & 63;
    const float scale = 0.125f;   // 1/sqrt(64)

    float qpv = qp[bh * NE + lane];
    float qnv = qn[bh * NE + lane];
    float Wg = sel_W[h * NG + lane];
    float Wp = fmaxf(Wg, 0.f), Wn = fminf(Wg, 0.f);

    __shared__ float ap_l[SC], an_l[SC];
    __shared__ float series_l[4][64];
    __shared__ float v_l[4][64];

    int s0 = chunk * SC;
    for (int i = 0; i < SC / 4; ++i) {
        int sl = i * 4 + wave;
        int s = s0 + sl;
        float kv = keys[(((size_t)(b * NL + s)) * NH + h) * NE + lane];
        float ap = wave_sum(kv * qpv);
        float an = wave_sum(kv * qnv);
        if (lane == 0) { ap_l[sl] = ap; an_l[sl] = an; }
    }
    __syncthreads();

    int g = threadIdx.x & 63;
    int e0 = (threadIdx.x >> 6) * 16;
    float acc[16];
    #pragma unroll
    for (int j = 0; j < 16; ++j) acc[j] = 0.f;

    for (int i = 0; i < SC / 4; ++i) {
        int sl = i * 4 + wave;
        int s = s0 + sl;
        float ap = ap_l[sl], an = an_l[sl];
        float logit = scale * (Wp * ap + Wn * an);
        float m = wave_max(logit);
        float p = __expf(logit - m);
        float denom = wave_sum(p);
        series_l[wave][lane] = p / denom;
        v_l[wave][lane] = values[(((size_t)(b * NL + s)) * NH + h) * NE + lane];
        __syncthreads();
        #pragma unroll
        for (int si = 0; si < 4; ++si) {
            float sv = series_l[si][g];
            const float4* vrow = (const float4*)&v_l[si][e0];
            #pragma unroll
            for (int jj = 0; jj < 4; ++jj) {
                float4 vv = vrow[jj];
                acc[jj * 4 + 0] += vv.x * sv;
                acc[jj * 4 + 1] += vv.y * sv;
                acc[jj * 4 + 2] += vv.z * sv;
                acc[jj * 4 + 3] += vv.w * sv;
            }
        }
        __syncthreads();
    }

    float* outb = out + (size_t)b * (NE * NH * NG) + (size_t)h * NG;
    #pragma unroll
    for (int j = 0; j < 16; ++j)
        atomicAdd(&outb[(size_t)(e0 + j) * (NH * NG) + g], acc[j]);
}

extern "C" void kernel_launch(void* const* d_in, const int* in_sizes, int n_in,
                              void* d_out, int out_size, void* d_ws, size_t ws_size,
                              hipStream_t stream) {
    (void)in_sizes; (void)n_in; (void)ws_size;
    const float* queries = (const float*)d_in[0];
    const float* keys    = (const float*)d_in[1];
    const float* values  = (const float*)d_in[2];
    const float* x       = (const float*)d_in[3];
    const float* mlp_w   = (const float*)d_in[4];
    const float* mlp_b   = (const float*)d_in[5];
    const float* sel_W   = (const float*)d_in[6];
    float* out = (float*)d_out;

    // ws layout (floats): t[131072] | qp[8192] | qn[8192]
    float* t_ws = (float*)d_ws;
    float* qp_ws = t_ws + NB * NH * NL;
    float* qn_ws = qp_ws + NB * NH * NE;

    // zero the atomic-accumulated buffers (d_out and qp/qn are poisoned 0xAA)
    hipMemsetAsync(out, 0, (size_t)out_size * sizeof(float), stream);
    hipMemsetAsync(qp_ws, 0, (size_t)2 * NB * NH * NE * sizeof(float), stream);

    k_tanh_mlp<<<dim3(NB * NL / 4), dim3(256), 0, stream>>>(x, mlp_w, mlp_b, t_ws);
    k_qpn<<<dim3(NB * NH * 4), dim3(256), 0, stream>>>(queries, t_ws, qp_ws, qn_ws);
    k_attn_out<<<dim3(NB * NH * 8), dim3(256), 0, stream>>>(keys, values, sel_W,
                                                            qp_ws, qn_ws, out);
}